// Round 9
// baseline (100.648 us; speedup 1.0000x reference)
//
#include <hip/hip_runtime.h>
#include <math.h>

// Problem constants (B,C,H,W = 16,64,256,256; RATIO=2, GROUPS=4)
#define BATCH 16
#define CIN   64
#define HIN   256
#define WIN   256
#define HOUT  128
#define WOUT  128
#define NPIX  (HIN * WIN)          // 65536
#define NPIXO (HOUT * WOUT)        // 16384
#define OUT0_SIZE ((size_t)BATCH * CIN * HOUT * WOUT)   // 16777216

typedef __attribute__((ext_vector_type(4))) float f32x4;

// ---------------------------------------------------------------------------
// Fully fused kernel, v3b (= v3 with the missing batch offset in the out
// store fixed: out index must include b*CIN*NPIXO).
//
// Phase 1: lane pairs cooperatively load float4 (even lane = top row,
//   odd = bottom row of the 2x2 conv block); 8 shuffles reassemble.
//   64 loads/thread instead of 128. Each input pixel still read exactly
//   once chip-wide (phase-2 gathers then hit L3).
//
// Phase 2: wave-uniform cooperative fast path — pair lanes load one
//   float4 each (row y0 / row y1), compute bilinear row-partials for both
//   pixels, merge with one shuffle per channel. 64 gathers instead of 128.
//   Per-lane float2/scalar fallback preserves generality.
//
// Stores: LDS transpose buffer at pitch 20 (16B-aligned rows) read back as
//   float4 -> 4 NT float4 stores per group instead of 16 scalar stores.
// ---------------------------------------------------------------------------
__global__ __launch_bounds__(256) void k_fused(
    const float* __restrict__ x,
    const float* __restrict__ w_off, const float* __restrict__ b_off,
    const float* __restrict__ w_sc,  const float* __restrict__ b_sc,
    float* __restrict__ out, float* __restrict__ offg)
{
    __shared__ float  sw[256];             // w_off ch0/ch1, w_sc ch0/ch1
    __shared__ float2 soff[4][16][17];     // [grp][row][col], padded
    __shared__ __align__(16) float sval[5184];  // 16 ch x pitch 324 floats

    int t = threadIdx.x;
    sw[t] = (t < 128) ? w_off[t] : w_sc[t - 128];

    int blk  = blockIdx.x;
    int b    = blk >> 6;
    int tile = blk & 63;
    int hh0  = (tile >> 3) * 16;
    int ww0  = (tile & 7) * 16;

    // ---------------- phase 1: conv1x1 offsets (pair-cooperative) ----------
    int row = t >> 4, col = t & 15;
    int hh = hh0 + row, ww = ww0 + col;
    int odd = t & 1;
    int colbase = 2 * (ww0 + (col & 14));   // pair's input col base (x4 aligned)

    const float* xrow = x + (size_t)b * CIN * NPIX
                      + (size_t)(2 * hh + odd) * WIN + colbase;

    float TA0[4] = {0,0,0,0}, TA1[4] = {0,0,0,0};
    float TS0[4] = {0,0,0,0}, TS1[4] = {0,0,0,0};

    __syncthreads();   // sw ready

    #pragma unroll 8
    for (int c = 0; c < CIN; ++c) {
        f32x4 f = *reinterpret_cast<const f32x4*>(xrow + (size_t)c * NPIX);
        float wo0 = sw[c], wo1 = sw[64 + c], ws0 = sw[128 + c], ws1 = sw[192 + c];
        #pragma unroll
        for (int j = 0; j < 4; ++j) {
            TA0[j] += f[j] * wo0;
            TA1[j] += f[j] * wo1;
            TS0[j] += f[j] * ws0;
            TS1[j] += f[j] * ws1;
        }
    }

    // pair exchange: even lane holds TOP-row sums (4 cols), odd BOTTOM-row.
    float rA0_0 = __shfl_xor(odd ? TA0[0] : TA0[2], 1);
    float rA0_1 = __shfl_xor(odd ? TA0[1] : TA0[3], 1);
    float rA1_0 = __shfl_xor(odd ? TA1[0] : TA1[2], 1);
    float rA1_1 = __shfl_xor(odd ? TA1[1] : TA1[3], 1);
    float rS0_0 = __shfl_xor(odd ? TS0[0] : TS0[2], 1);
    float rS0_1 = __shfl_xor(odd ? TS0[1] : TS0[3], 1);
    float rS1_0 = __shfl_xor(odd ? TS1[0] : TS1[2], 1);
    float rS1_1 = __shfl_xor(odd ? TS1[1] : TS1[3], 1);

    // 2x2 per-pixel sums: a{row}{col} per conv output channel pair
    float aA0[2][2], aA1[2][2], aS0[2][2], aS1[2][2];
    aA0[0][0] = odd ? rA0_0 : TA0[0];  aA0[0][1] = odd ? rA0_1 : TA0[1];
    aA0[1][0] = odd ? TA0[2] : rA0_0;  aA0[1][1] = odd ? TA0[3] : rA0_1;
    aA1[0][0] = odd ? rA1_0 : TA1[0];  aA1[0][1] = odd ? rA1_1 : TA1[1];
    aA1[1][0] = odd ? TA1[2] : rA1_0;  aA1[1][1] = odd ? TA1[3] : rA1_1;
    aS0[0][0] = odd ? rS0_0 : TS0[0];  aS0[0][1] = odd ? rS0_1 : TS0[1];
    aS0[1][0] = odd ? TS0[2] : rS0_0;  aS0[1][1] = odd ? TS0[3] : rS0_1;
    aS1[0][0] = odd ? rS1_0 : TS1[0];  aS1[0][1] = odd ? rS1_1 : TS1[1];
    aS1[1][0] = odd ? TS1[2] : rS1_0;  aS1[1][1] = odd ? TS1[3] : rS1_1;

    float bo0 = b_off[0], bo1 = b_off[1];
    float bs0 = b_sc[0],  bs1 = b_sc[1];

    float og[4][2];
    #pragma unroll
    for (int i = 0; i < 2; ++i) {
        #pragma unroll
        for (int j = 0; j < 2; ++j) {
            float g0 = 1.0f / (1.0f + __expf(-(aS0[i][j] + bs0)));
            float g1 = 1.0f / (1.0f + __expf(-(aS1[i][j] + bs1)));
            og[i][j]     = g0 * 0.5f * (aA0[i][j] + bo0);
            og[2 + i][j] = g1 * 0.5f * (aA1[i][j] + bo1);
        }
    }

    #pragma unroll
    for (int g = 0; g < 4; ++g) {
        float2 vv = make_float2(og[g][0], og[g][1]);
        soff[g][row][col] = vv;
        size_t oi = ((size_t)((b * 4 + g) * HOUT + hh)) * WOUT + ww;
        __builtin_nontemporal_store(__builtin_bit_cast(double, vv),
                                    reinterpret_cast<double*>(offg + 2 * oi));
    }
    __syncthreads();

    // ---------------- phase 2: bilinear grid sample ------------------------
    int hl = t & 15, wl = t >> 4;          // hh-fast gather mapping
    int shh = hh0 + hl, sww = ww0 + wl;
    int oddl = t & 1;
    const float* xg = x + (size_t)b * CIN * NPIX;

    int R  = (t >> 2) & 15;                // store mapping: row
    int q  = t & 3;                        // store mapping: quad (x4 floats)
    int wv = t >> 6;                       // wave id 0..3

    // out base for this block's batch (bug fix: include b*CIN*NPIXO)
    float* outb = out + (size_t)b * CIN * NPIXO
                + (size_t)(hh0 + R) * WOUT + ww0 + q * 4;

    #pragma unroll
    for (int g = 0; g < 4; ++g) {
        float2 off = soff[g][hl][wl];
        // transposed coords: ix (column) from hh, iy (row) from ww
        float ix = 2.0f * ((float)shh + 0.5f + off.x) - 0.5f;
        float iy = 2.0f * ((float)sww + 0.5f + off.y) - 0.5f;
        ix = fminf(fmaxf(ix, 0.0f), (float)(WIN - 1));
        iy = fminf(fmaxf(iy, 0.0f), (float)(HIN - 1));

        float x0f = floorf(ix), y0f = floorf(iy);
        float wx = ix - x0f, wy = iy - y0f;
        int x0 = (int)x0f, y0 = (int)y0f;
        int x1 = min(x0 + 1, WIN - 1);
        int y1 = min(y0 + 1, HIN - 1);

        float w00 = (1.0f - wx) * (1.0f - wy);
        float w01 = wx * (1.0f - wy);
        float w10 = (1.0f - wx) * wy;
        float w11 = wx * wy;

        const float* xgc = xg + (size_t)g * NPIX;   // channel c*4+g

        // pair-cooperative predicate (wave-uniform branch)
        int x0p = __shfl_xor(x0, 1);
        int y0p = __shfl_xor(y0, 1);
        bool ok = (x1 == x0 + 1) && (y1 == y0 + 1) && (y0p == y0)
               && (oddl ? (x0 == x0p + 2) : (x0p == x0 + 2))
               && (((x0 - (oddl ? 2 : 0)) & 3) == 0);

        float v[16];
        if (__all(ok)) {
            int colb = x0 - (oddl ? 2 : 0);
            int rowL = oddl ? y1 : y0;
            float rw0 = __shfl_xor(oddl ? w00 : w10, 1);
            float rw1 = __shfl_xor(oddl ? w01 : w11, 1);
            const float* basep = xgc + (size_t)rowL * WIN + colb;
            #pragma unroll
            for (int c = 0; c < 16; ++c) {
                f32x4 f = *reinterpret_cast<const f32x4*>(basep + (size_t)c * 4 * NPIX);
                float pOwn  = oddl ? (f[2] * w10 + f[3] * w11)
                                   : (f[0] * w00 + f[1] * w01);
                float pPart = oddl ? (f[0] * rw0 + f[1] * rw1)
                                   : (f[2] * rw0 + f[3] * rw1);
                v[c] = pOwn + __shfl_xor(pPart, 1);
            }
        } else {
            int i00 = y0 * WIN + x0, i01 = y0 * WIN + x1;
            int i10 = y1 * WIN + x0, i11 = y1 * WIN + x1;
            bool fastp = ((x0 & 1) == 0) && (x1 == x0 + 1);
            if (fastp) {
                #pragma unroll
                for (int c = 0; c < 16; ++c) {
                    const float* xc = xgc + (size_t)c * 4 * NPIX;
                    float2 a = *reinterpret_cast<const float2*>(xc + i00);
                    float2 d = *reinterpret_cast<const float2*>(xc + i10);
                    v[c] = a.x * w00 + a.y * w01 + d.x * w10 + d.y * w11;
                }
            } else {
                #pragma unroll
                for (int c = 0; c < 16; ++c) {
                    const float* xc = xgc + (size_t)c * 4 * NPIX;
                    v[c] = xc[i00] * w00 + xc[i01] * w01
                         + xc[i10] * w10 + xc[i11] * w11;
                }
            }
        }

        __syncthreads();   // previous group's sval reads complete
        #pragma unroll
        for (int c = 0; c < 16; ++c)
            sval[c * 324 + hl * 20 + wl] = v[c];
        __syncthreads();   // sval ready

        // vectorized coalesced NT stores: 4 lanes cover one 64B row segment
        #pragma unroll
        for (int p2 = 0; p2 < 4; ++p2) {
            int c = wv * 4 + p2;
            f32x4 val = *reinterpret_cast<const f32x4*>(&sval[c * 324 + R * 20 + q * 4]);
            __builtin_nontemporal_store(val, reinterpret_cast<f32x4*>(
                outb + (size_t)(c * 4 + g) * NPIXO));
        }
    }
}

extern "C" void kernel_launch(void* const* d_in, const int* in_sizes, int n_in,
                              void* d_out, int out_size, void* d_ws, size_t ws_size,
                              hipStream_t stream) {
    const float* x     = (const float*)d_in[0];
    const float* w_off = (const float*)d_in[1];
    const float* b_off = (const float*)d_in[2];
    const float* w_sc  = (const float*)d_in[3];
    const float* b_sc  = (const float*)d_in[4];

    float* out  = (float*)d_out;
    float* offg = out + OUT0_SIZE;   // second return value, concatenated

    // 16 batches x 64 tiles = 1024 blocks of 256 threads (whole grid resident)
    k_fused<<<1024, 256, 0, stream>>>(x, w_off, b_off, w_sc, b_sc, out, offg);
}

// Round 10
// 99.194 us; speedup vs baseline: 1.0147x; 1.0147x over previous
//
#include <hip/hip_runtime.h>
#include <math.h>

// Problem constants (B,C,H,W = 16,64,256,256; RATIO=2, GROUPS=4)
#define BATCH 16
#define CIN   64
#define HIN   256
#define WIN   256
#define HOUT  128
#define WOUT  128
#define NPIX  (HIN * WIN)          // 65536
#define NPIXO (HOUT * WOUT)        // 16384
#define OUT0_SIZE ((size_t)BATCH * CIN * NPIXO)   // 16777216

typedef __attribute__((ext_vector_type(4))) float f32x4;

// ---------------------------------------------------------------------------
// v4: producer/consumer wave-specialized pipeline (phase overlap).
//
// Evidence: r6/r7/r9 all ~100us regardless of occupancy and VMEM instruction
// count, FETCH pinned at 268MB -> chip executes phase1 (HBM, ~43us) and
// phase2 (L3 gathers, ~55us) back-to-back with the other pipe idle.
//
// Structure: 256 blocks x 512 threads (1 block/CU). Waves 0-3 = conv engine
// (r9's phase-1 code), waves 4-7 = sample engine (r9's phase-2 code).
// Block owns 4 tiles: p = k>>1 fixed, q in [4j,4j+4). Round r (r=0..4):
//   producers conv tile with q=((r-p)&3)+4j  (64 ch in 4 chunks of 16,
//     one chunk per sub-round), write soff[r&1] + offg at sub-round 3;
//   consumers sample previous round's tile from soff[(r-1)&1], one group
//     per sub-round, with a one-sub-round-delayed store pipeline through
//     double-buffered sval[g&1].
// One __syncthreads per sub-round (outside all divergence) serves every
// LDS hazard. Round slot (p+q)&3 is symmetric so tile (p,q) and its
// gather-partner (q,p) are conv'd chip-wide in the same round -> sample
// gathers stay L3-resident.
// ---------------------------------------------------------------------------
__global__ __launch_bounds__(512, 1) void k_fused(
    const float* __restrict__ x,
    const float* __restrict__ w_off, const float* __restrict__ b_off,
    const float* __restrict__ w_sc,  const float* __restrict__ b_sc,
    float* __restrict__ out, float* __restrict__ offg)
{
    __shared__ float  sw[256];                 // conv weights
    __shared__ float2 soff[2][4][16][17];      // offsets, dbuf by round
    __shared__ __align__(16) float sval[2][5184];  // transpose, dbuf by group

    const int t = threadIdx.x;
    if (t < 256) sw[t] = (t < 128) ? w_off[t] : w_sc[t - 128];

    const int blk = blockIdx.x;      // [0,256)
    const int b   = blk >> 4;
    const int k   = blk & 15;
    const int pr  = k >> 1;          // tile row (fixed for this block)
    const int jj  = k & 1;           // q half
    const int hh0 = pr * 16;

    const bool isProd = (t < 256);   // waves 0-3 produce, 4-7 consume
    const int u = t & 255;

    // ---- producer per-thread constants (r9 phase-1 mapping) ----
    const int prow = u >> 4, pcol = u & 15;
    const int phh  = hh0 + prow;
    const int podd = u & 1;
    const float* xbase = x + (size_t)b * CIN * NPIX
                       + (size_t)(2 * phh + podd) * WIN;
    float bo0 = 0, bo1 = 0, bs0 = 0, bs1 = 0;
    if (isProd) { bo0 = b_off[0]; bo1 = b_off[1]; bs0 = b_sc[0]; bs1 = b_sc[1]; }

    // ---- consumer per-thread constants (r9 phase-2 mapping) ----
    const int hl = u & 15, wl = u >> 4;   // hh-fast gather mapping
    const int shh = hh0 + hl;
    const int oddl = u & 1;
    const float* xg = x + (size_t)b * CIN * NPIX;
    const int Rr = (u >> 2) & 15, q4 = u & 3, wv = u >> 6;  // store mapping
    float* outTB = out + (size_t)b * CIN * NPIXO
                 + (size_t)(hh0 + Rr) * WOUT + q4 * 4;

    int prev_ww0 = 0;   // consumer: previous round's tile col base

    __syncthreads();    // sw ready

    for (int r = 0; r < 5; ++r) {
        const bool prodA = (r <= 3);
        const bool consA = (r >= 1);
        const int qp = ((r - pr) & 3) + 4 * jj;         // producer tile col
        const int qc = (((r - 1) - pr) & 3) + 4 * jj;   // consumer tile col
        const int ww0p = qp * 16;
        const int ww0c = qc * 16;

        // conv accumulators for this round's tile
        float TA0[4] = {0,0,0,0}, TA1[4] = {0,0,0,0};
        float TS0[4] = {0,0,0,0}, TS1[4] = {0,0,0,0};

        #pragma unroll
        for (int g = 0; g < 4; ++g) {
            if (isProd) {
                if (prodA) {
                    // ---- conv chunk: channels [16g, 16g+16) ----
                    const float* xrow = xbase + 2 * (ww0p + (pcol & 14));
                    #pragma unroll
                    for (int ci = 0; ci < 16; ++ci) {
                        const int c = g * 16 + ci;
                        f32x4 f = *reinterpret_cast<const f32x4*>(
                            xrow + (size_t)c * NPIX);
                        float wo0 = sw[c], wo1 = sw[64 + c];
                        float ws0 = sw[128 + c], ws1 = sw[192 + c];
                        #pragma unroll
                        for (int jx = 0; jx < 4; ++jx) {
                            TA0[jx] += f[jx] * wo0;
                            TA1[jx] += f[jx] * wo1;
                            TS0[jx] += f[jx] * ws0;
                            TS1[jx] += f[jx] * ws1;
                        }
                    }
                    if (g == 3) {
                        // ---- offsets epilogue (r9 verbatim) ----
                        float rA0_0 = __shfl_xor(podd ? TA0[0] : TA0[2], 1);
                        float rA0_1 = __shfl_xor(podd ? TA0[1] : TA0[3], 1);
                        float rA1_0 = __shfl_xor(podd ? TA1[0] : TA1[2], 1);
                        float rA1_1 = __shfl_xor(podd ? TA1[1] : TA1[3], 1);
                        float rS0_0 = __shfl_xor(podd ? TS0[0] : TS0[2], 1);
                        float rS0_1 = __shfl_xor(podd ? TS0[1] : TS0[3], 1);
                        float rS1_0 = __shfl_xor(podd ? TS1[0] : TS1[2], 1);
                        float rS1_1 = __shfl_xor(podd ? TS1[1] : TS1[3], 1);

                        float aA0[2][2], aA1[2][2], aS0[2][2], aS1[2][2];
                        aA0[0][0] = podd ? rA0_0 : TA0[0];  aA0[0][1] = podd ? rA0_1 : TA0[1];
                        aA0[1][0] = podd ? TA0[2] : rA0_0;  aA0[1][1] = podd ? TA0[3] : rA0_1;
                        aA1[0][0] = podd ? rA1_0 : TA1[0];  aA1[0][1] = podd ? rA1_1 : TA1[1];
                        aA1[1][0] = podd ? TA1[2] : rA1_0;  aA1[1][1] = podd ? TA1[3] : rA1_1;
                        aS0[0][0] = podd ? rS0_0 : TS0[0];  aS0[0][1] = podd ? rS0_1 : TS0[1];
                        aS0[1][0] = podd ? TS0[2] : rS0_0;  aS0[1][1] = podd ? TS0[3] : rS0_1;
                        aS1[0][0] = podd ? rS1_0 : TS1[0];  aS1[0][1] = podd ? rS1_1 : TS1[1];
                        aS1[1][0] = podd ? TS1[2] : rS1_0;  aS1[1][1] = podd ? TS1[3] : rS1_1;

                        float og[4][2];
                        #pragma unroll
                        for (int i = 0; i < 2; ++i) {
                            #pragma unroll
                            for (int jy = 0; jy < 2; ++jy) {
                                float g0 = 1.0f / (1.0f + __expf(-(aS0[i][jy] + bs0)));
                                float g1 = 1.0f / (1.0f + __expf(-(aS1[i][jy] + bs1)));
                                og[i][jy]     = g0 * 0.5f * (aA0[i][jy] + bo0);
                                og[2 + i][jy] = g1 * 0.5f * (aA1[i][jy] + bo1);
                            }
                        }
                        #pragma unroll
                        for (int gg = 0; gg < 4; ++gg) {
                            float2 vv = make_float2(og[gg][0], og[gg][1]);
                            soff[r & 1][gg][prow][pcol] = vv;
                            size_t oi = ((size_t)((b * 4 + gg) * HOUT + phh)) * WOUT
                                      + (ww0p + pcol);
                            __builtin_nontemporal_store(
                                __builtin_bit_cast(double, vv),
                                reinterpret_cast<double*>(offg + 2 * oi));
                        }
                    }
                }
            } else {
                if (consA) {
                    // ---- pending store (one sub-round delayed) ----
                    if (g == 0) {
                        if (r >= 2) {
                            #pragma unroll
                            for (int p2 = 0; p2 < 4; ++p2) {
                                const int c = wv * 4 + p2;
                                f32x4 val = *reinterpret_cast<const f32x4*>(
                                    &sval[1][c * 324 + Rr * 20 + q4 * 4]);
                                __builtin_nontemporal_store(val,
                                    reinterpret_cast<f32x4*>(outTB + prev_ww0
                                        + (size_t)(c * 4 + 3) * NPIXO));
                            }
                        }
                    } else {
                        #pragma unroll
                        for (int p2 = 0; p2 < 4; ++p2) {
                            const int c = wv * 4 + p2;
                            f32x4 val = *reinterpret_cast<const f32x4*>(
                                &sval[(g - 1) & 1][c * 324 + Rr * 20 + q4 * 4]);
                            __builtin_nontemporal_store(val,
                                reinterpret_cast<f32x4*>(outTB + ww0c
                                    + (size_t)(c * 4 + (g - 1)) * NPIXO));
                        }
                    }

                    // ---- gather group g of this round's tile (r9 verbatim) ----
                    float2 off = soff[(r - 1) & 1][g][hl][wl];
                    const int sww = ww0c + wl;
                    float ix = 2.0f * ((float)shh + 0.5f + off.x) - 0.5f;  // col
                    float iy = 2.0f * ((float)sww + 0.5f + off.y) - 0.5f;  // row
                    ix = fminf(fmaxf(ix, 0.0f), (float)(WIN - 1));
                    iy = fminf(fmaxf(iy, 0.0f), (float)(HIN - 1));

                    float x0f = floorf(ix), y0f = floorf(iy);
                    float wx = ix - x0f, wy = iy - y0f;
                    int x0 = (int)x0f, y0 = (int)y0f;
                    int x1 = min(x0 + 1, WIN - 1);
                    int y1 = min(y0 + 1, HIN - 1);

                    float w00 = (1.0f - wx) * (1.0f - wy);
                    float w01 = wx * (1.0f - wy);
                    float w10 = (1.0f - wx) * wy;
                    float w11 = wx * wy;

                    const float* xgc = xg + (size_t)g * NPIX;

                    int x0p = __shfl_xor(x0, 1);
                    int y0p = __shfl_xor(y0, 1);
                    bool ok = (x1 == x0 + 1) && (y1 == y0 + 1) && (y0p == y0)
                           && (oddl ? (x0 == x0p + 2) : (x0p == x0 + 2))
                           && (((x0 - (oddl ? 2 : 0)) & 3) == 0);

                    float v[16];
                    if (__all(ok)) {
                        int colb = x0 - (oddl ? 2 : 0);
                        int rowL = oddl ? y1 : y0;
                        float rw0 = __shfl_xor(oddl ? w00 : w10, 1);
                        float rw1 = __shfl_xor(oddl ? w01 : w11, 1);
                        const float* basep = xgc + (size_t)rowL * WIN + colb;
                        #pragma unroll
                        for (int c = 0; c < 16; ++c) {
                            f32x4 f = *reinterpret_cast<const f32x4*>(
                                basep + (size_t)c * 4 * NPIX);
                            float pOwn  = oddl ? (f[2] * w10 + f[3] * w11)
                                               : (f[0] * w00 + f[1] * w01);
                            float pPart = oddl ? (f[0] * rw0 + f[1] * rw1)
                                               : (f[2] * rw0 + f[3] * rw1);
                            v[c] = pOwn + __shfl_xor(pPart, 1);
                        }
                    } else {
                        int i00 = y0 * WIN + x0, i01 = y0 * WIN + x1;
                        int i10 = y1 * WIN + x0, i11 = y1 * WIN + x1;
                        bool fastp = ((x0 & 1) == 0) && (x1 == x0 + 1);
                        if (fastp) {
                            #pragma unroll
                            for (int c = 0; c < 16; ++c) {
                                const float* xc = xgc + (size_t)c * 4 * NPIX;
                                float2 a = *reinterpret_cast<const float2*>(xc + i00);
                                float2 d = *reinterpret_cast<const float2*>(xc + i10);
                                v[c] = a.x * w00 + a.y * w01 + d.x * w10 + d.y * w11;
                            }
                        } else {
                            #pragma unroll
                            for (int c = 0; c < 16; ++c) {
                                const float* xc = xgc + (size_t)c * 4 * NPIX;
                                v[c] = xc[i00] * w00 + xc[i01] * w01
                                     + xc[i10] * w10 + xc[i11] * w11;
                            }
                        }
                    }

                    #pragma unroll
                    for (int c = 0; c < 16; ++c)
                        sval[g & 1][c * 324 + hl * 20 + wl] = v[c];
                }
            }
            __syncthreads();   // single uniform barrier per sub-round
        }
        if (!isProd && consA) prev_ww0 = ww0c;
    }

    // final drain: group 3 of the round-4 consumer tile (sval[1])
    if (!isProd) {
        #pragma unroll
        for (int p2 = 0; p2 < 4; ++p2) {
            const int c = wv * 4 + p2;
            f32x4 val = *reinterpret_cast<const f32x4*>(
                &sval[1][c * 324 + Rr * 20 + q4 * 4]);
            __builtin_nontemporal_store(val,
                reinterpret_cast<f32x4*>(outTB + prev_ww0
                    + (size_t)(c * 4 + 3) * NPIXO));
        }
    }
}

extern "C" void kernel_launch(void* const* d_in, const int* in_sizes, int n_in,
                              void* d_out, int out_size, void* d_ws, size_t ws_size,
                              hipStream_t stream) {
    const float* x     = (const float*)d_in[0];
    const float* w_off = (const float*)d_in[1];
    const float* b_off = (const float*)d_in[2];
    const float* w_sc  = (const float*)d_in[3];
    const float* b_sc  = (const float*)d_in[4];

    float* out  = (float*)d_out;
    float* offg = out + OUT0_SIZE;   // second return value, concatenated

    // 256 blocks (1 per CU) x 512 threads: 4 producer + 4 consumer waves
    k_fused<<<256, 512, 0, stream>>>(x, w_off, b_off, w_sc, b_sc, out, offg);
}